// Round 11
// baseline (518.681 us; speedup 1.0000x reference)
//
#include <hip/hip_runtime.h>

// HeteroGNN on MI355X — round 11: pre-scaled gather rows (xd = dinv*x stored
// bf16) remove the per-edge dinv load + multiply from both aggregation passes.
// Layer-1 GEMM epilogue dual-writes pb (unscaled) + pbd (dinv-scaled).

#define DP   256
#define DA   128
#define HIDN 256
#define DOUT 349
#define NBKT 782          // ceil(100000/128)
#define CHUNK 4096

typedef unsigned short u16;
typedef unsigned int u32;
typedef __attribute__((ext_vector_type(8))) short bf16x8;
typedef __attribute__((ext_vector_type(4))) float f32x4;

__device__ __forceinline__ u16 bf16_rn(float x) {
  union { float f; unsigned u; } v; v.f = x;
  unsigned r = v.u + 0x7FFFu + ((v.u >> 16) & 1u);
  return (u16)(r >> 16);
}
__device__ __forceinline__ float bf16f(u16 h) {
  union { float f; unsigned u; } v; v.u = ((unsigned)h) << 16; return v.f;
}
__device__ __forceinline__ unsigned pack2(float a, float b) {
  return (unsigned)bf16_rn(a) | ((unsigned)bf16_rn(b) << 16);
}

__device__ __forceinline__ void gload16(const void* g, void* lds) {
  __builtin_amdgcn_global_load_lds(
      (const __attribute__((address_space(1))) unsigned int*)g,
      (__attribute__((address_space(3))) unsigned int*)lds, 16, 0, 0);
}

// ---------------- exclusive scan (2048/block) ----------------
#define SCAN_TPB 256
#define SCAN_VPT 8
#define SCAN_TILE 2048

__global__ void scan_local(const int* __restrict__ in, int* __restrict__ out,
                           int* __restrict__ bsum, int n) {
  __shared__ int sdata[SCAN_TPB];
  int t = threadIdx.x;
  int base = blockIdx.x * SCAN_TILE + t * SCAN_VPT;
  int v[SCAN_VPT];
  int sum = 0;
#pragma unroll
  for (int j = 0; j < SCAN_VPT; ++j) {
    int idx = base + j;
    v[j] = (idx < n) ? in[idx] : 0;
    sum += v[j];
  }
  sdata[t] = sum;
  __syncthreads();
  for (int off = 1; off < SCAN_TPB; off <<= 1) {
    int x = (t >= off) ? sdata[t - off] : 0;
    __syncthreads();
    sdata[t] += x;
    __syncthreads();
  }
  int prefix = sdata[t] - sum;
  if (t == SCAN_TPB - 1) bsum[blockIdx.x] = sdata[t];
  int run = prefix;
#pragma unroll
  for (int j = 0; j < SCAN_VPT; ++j) {
    int idx = base + j;
    if (idx < n) out[idx] = run;
    run += v[j];
  }
}

__global__ void scan_spine(int* __restrict__ bsum, int nb) {
  __shared__ int sdata[256];
  int t = threadIdx.x;
  int v = (t < nb) ? bsum[t] : 0;
  sdata[t] = v;
  __syncthreads();
  for (int off = 1; off < 256; off <<= 1) {
    int x = (t >= off) ? sdata[t - off] : 0;
    __syncthreads();
    sdata[t] += x;
    __syncthreads();
  }
  if (t < nb) bsum[t] = sdata[t] - v;
}

__global__ void scan_add(int* __restrict__ out, const int* __restrict__ bsum, int n) {
  int add = bsum[blockIdx.x];
  int base = blockIdx.x * SCAN_TILE + threadIdx.x * SCAN_VPT;
#pragma unroll
  for (int j = 0; j < SCAN_VPT; ++j) {
    int idx = base + j;
    if (idx < n) out[idx] += add;
  }
}

// -------- sort pass 1 (both edge types): chunk -> bucketed packed tmp (u32) ----
__global__ __launch_bounds__(256) void sort_pass1(
    const int* __restrict__ c_src, const int* __restrict__ c_dst,
    const int* __restrict__ w_srcP, const int* __restrict__ w_dstP,
    u32* __restrict__ tmp, int* __restrict__ gcount, int* __restrict__ lofs,
    int E, int nch) {
  const int cg = blockIdx.x, t = threadIdx.x;
  const int et = cg >= nch;
  const int c = cg - et * nch;
  const int* src = et ? w_srcP : c_src;
  const int* dst = et ? w_dstP : c_dst;
  __shared__ u32 cnt[NBKT];
  __shared__ u32 ofs[NBKT];
  __shared__ u32 sdata[256];
  __shared__ u32 pay[CHUNK];
  __shared__ u16 bkt[CHUNK];

  for (int i = t; i < NBKT; i += 256) cnt[i] = 0;
  __syncthreads();
  const int base = c * CHUNK;
#pragma unroll
  for (int j = 0; j < 16; ++j) {
    int i = t + j * 256, idx = base + i;
    if (idx < E) {
      u32 s = (u32)src[idx], d = (u32)dst[idx];
      pay[i] = (s << 7) | (d & 127u);
      bkt[i] = (u16)(d >> 7);
      atomicAdd(&cnt[d >> 7], 1u);
    }
  }
  __syncthreads();
  for (int i = t; i < NBKT; i += 256)
    gcount[((size_t)et * NBKT + i) * nch + c] = (int)cnt[i];
  u32 ssum = 0;
  const int b0 = t * 4;
#pragma unroll
  for (int j = 0; j < 4; ++j) {
    int i = b0 + j;
    if (i < NBKT) ssum += cnt[i];
  }
  sdata[t] = ssum;
  __syncthreads();
  for (int o = 1; o < 256; o <<= 1) {
    u32 x = (t >= o) ? sdata[t - o] : 0;
    __syncthreads();
    sdata[t] += x;
    __syncthreads();
  }
  u32 run = sdata[t] - ssum;
#pragma unroll
  for (int j = 0; j < 4; ++j) {
    int i = b0 + j;
    if (i < NBKT) { ofs[i] = run; run += cnt[i]; }
  }
  __syncthreads();
  for (int i = t; i < NBKT; i += 256) {
    lofs[((size_t)et * nch + c) * NBKT + i] = (int)ofs[i];
    cnt[i] = ofs[i];
  }
  __syncthreads();
  u32* tout = tmp + (size_t)et * nch * CHUNK + base;
#pragma unroll
  for (int j = 0; j < 16; ++j) {
    int i = t + j * 256, idx = base + i;
    if (idx < E) {
      u32 p = atomicAdd(&cnt[bkt[i]], 1u);
      tout[p] = pay[i];
    }
  }
}

// -------- sort pass 2 (both edge types): bucket -> sorted + deg + off (+dinv) ---
#define MAXB 2560
__global__ __launch_bounds__(256) void sort_pass2(
    const u32* __restrict__ tmp, const int* __restrict__ prefix,
    const int* __restrict__ gcount, const int* __restrict__ lofs,
    int* __restrict__ cSorted, int* __restrict__ cDeg, int* __restrict__ cOff,
    int* __restrict__ wSorted, int* __restrict__ wDeg, int* __restrict__ wOff,
    float* __restrict__ dinv,
    int E, int nch, int n, int nbk) {
  const int bg = blockIdx.x, t = threadIdx.x;
  const int et = bg >= nbk;
  const int b = bg - et * nbk;
  int* outSorted = et ? wSorted : cSorted;
  int* deg = et ? wDeg : cDeg;
  int* offArr = et ? wOff : cOff;
  __shared__ u32 est[MAXB];
  __shared__ u32 outl[MAXB];
  __shared__ u32 cnt[128], ofs[128];
  __shared__ u32 sdata[256];

  const int node0 = b << 7;
  const size_t bgl = (size_t)et * NBKT + b;
  const int ebaseG = prefix[bgl * nch];
  const int eendG = (bg == 2 * nbk - 1) ? 2 * E : prefix[(bgl + 1) * nch];
  const int ebase = ebaseG - et * E;
  const int esize = (eendG - et * E) - ebase;

  const u32* tsrc = tmp + (size_t)et * nch * CHUNK;
  for (int c = t; c < nch; c += 256) {
    int g = lofs[((size_t)et * nch + c) * NBKT + b];
    int len = gcount[bgl * nch + c];
    int dp = prefix[bgl * nch + c] - ebaseG;
    for (int k = 0; k < len; ++k)
      est[dp + k] = tsrc[(size_t)c * CHUNK + g + k];
  }
  if (t < 128) cnt[t] = 0;
  __syncthreads();
  for (int i = t; i < esize; i += 256) atomicAdd(&cnt[est[i] & 127u], 1u);
  __syncthreads();
  u32 v = (t < 128) ? cnt[t] : 0;
  sdata[t] = v;
  __syncthreads();
  for (int o = 1; o < 256; o <<= 1) {
    u32 x = (t >= o) ? sdata[t - o] : 0;
    __syncthreads();
    sdata[t] += x;
    __syncthreads();
  }
  if (t < 128) ofs[t] = sdata[t] - v;
  __syncthreads();
  const int nNodes = (n - node0) < 128 ? (n - node0) : 128;
  if (t < nNodes) {
    deg[node0 + t] = (int)cnt[t];
    offArr[node0 + t] = ebase + (int)ofs[t];
    if (et == 0) dinv[node0 + t] = rsqrtf((float)(cnt[t] + 1));
  }
  __syncthreads();
  if (t < 128) cnt[t] = ofs[t];
  __syncthreads();
  for (int i = t; i < esize; i += 256) {
    u32 e = est[i];
    u32 p = atomicAdd(&cnt[e & 127u], 1u);
    outl[p] = e >> 7;
  }
  __syncthreads();
  for (int i = t; i < esize; i += 256) outSorted[ebase + i] = (int)outl[i];
}

// ---------------- fused prep: convs (+scaled paper copy) + weights + biases ----
__global__ void prep_all(
    const float* __restrict__ x_paper, const float* __restrict__ x_author,
    const float* __restrict__ dinv,
    u16* __restrict__ xp, u16* __restrict__ xpd, u16* __restrict__ xa16,
    const float* __restrict__ W1, const float* __restrict__ Wr1,
    const float* __restrict__ W2, const float* __restrict__ Wr2,
    const float* __restrict__ Wl1, const float* __restrict__ Wl2,
    const float* __restrict__ linW,
    u16* __restrict__ BtW1, u16* __restrict__ BtWr1,
    u16* __restrict__ BtW2, u16* __restrict__ BtWr2,
    u16* __restrict__ BtWl1, u16* __restrict__ BtWl2, u16* __restrict__ BtLin,
    const float* __restrict__ b1, const float* __restrict__ bl1,
    const float* __restrict__ b2, const float* __restrict__ bl2,
    const float* __restrict__ linb,
    float* __restrict__ biasR1, float* __restrict__ biasR2,
    float* __restrict__ biasLin,
    int N, int NA) {
  const int R1 = (N * 32 + 255) / 256;
  const int R2 = R1 + (NA * 16 + 255) / 256;
  const int WB = 256 * 256 / 256;
  const int LB = 256 * 128 / 256;
  const int FB = 384 * 256 / 256;
  int bid = blockIdx.x, t = threadIdx.x;

  if (bid < R1) {
    int i = bid * 256 + t;
    if (i < N * 32) {
      int row = i >> 5;
      float dv = dinv[row];
      const float4* x4 = (const float4*)x_paper;
      float4 v0 = x4[(size_t)i * 2];
      float4 v1 = x4[(size_t)i * 2 + 1];
      uint4 O, S;
      O.x = pack2(v0.x, v0.y); O.y = pack2(v0.z, v0.w);
      O.z = pack2(v1.x, v1.y); O.w = pack2(v1.z, v1.w);
      S.x = pack2(v0.x * dv, v0.y * dv); S.y = pack2(v0.z * dv, v0.w * dv);
      S.z = pack2(v1.x * dv, v1.y * dv); S.w = pack2(v1.z * dv, v1.w * dv);
      ((uint4*)xp)[i] = O;
      ((uint4*)xpd)[i] = S;
    }
    return;
  }
  if (bid < R2) {
    int i = (bid - R1) * 256 + t;
    if (i < NA * 16) {
      const float4* x4 = (const float4*)x_author;
      float4 v0 = x4[(size_t)i * 2];
      float4 v1 = x4[(size_t)i * 2 + 1];
      uint4 O;
      O.x = pack2(v0.x, v0.y); O.y = pack2(v0.z, v0.w);
      O.z = pack2(v1.x, v1.y); O.w = pack2(v1.z, v1.w);
      ((uint4*)xa16)[i] = O;
    }
    return;
  }
  int wb = bid - R2;
  const float* W; u16* Bt; int K, Nn, Npad;
  if      (wb < WB)                  { W = W1;  Bt = BtW1;  K = 256; Nn = 256; Npad = 256; }
  else if ((wb -= WB) < WB)          { W = Wr1; Bt = BtWr1; K = 256; Nn = 256; Npad = 256; }
  else if ((wb -= WB) < WB)          { W = W2;  Bt = BtW2;  K = 256; Nn = 256; Npad = 256; }
  else if ((wb -= WB) < WB)          { W = Wr2; Bt = BtWr2; K = 256; Nn = 256; Npad = 256; }
  else if ((wb -= WB) < LB)          { W = Wl1; Bt = BtWl1; K = 128; Nn = 256; Npad = 256; }
  else if ((wb -= LB) < LB)          { W = Wl2; Bt = BtWl2; K = 128; Nn = 256; Npad = 256; }
  else if ((wb -= LB) < FB)          { W = linW; Bt = BtLin; K = 256; Nn = DOUT; Npad = 384; }
  else {
    if (t < 256) {
      biasR1[t] = b1[t] + bl1[t];
      biasR2[t] = b2[t] + bl2[t];
    }
    for (int i = t; i < 384; i += 256) biasLin[i] = (i < DOUT) ? linb[i] : 0.f;
    return;
  }
  int idx = wb * 256 + t;
  int tot = Npad * K;
  if (idx >= tot) return;
  int nn = idx / K, k = idx - nn * K;
  float v = (nn < Nn) ? W[(size_t)k * Nn + nn] : 0.f;
  Bt[idx] = bf16_rn(v);
}

// ---- wide gather bodies (pre-scaled rows: pure row sums) ----------------------
// cites agg: row = 512B = 32 uint4; 32 lanes cover a row; 2 edges/wave (halves).
__device__ __forceinline__ void agg_body(
    const uint4* __restrict__ base, const float* __restrict__ dinv,
    const int* __restrict__ c_off, const int* __restrict__ c_cnt,
    const int* __restrict__ c_sorted, u16* __restrict__ xout,
    int d, int lane) {
  const int hl = lane & 31;
  const int half = lane >> 5;
  int start = c_off[d], cnt = c_cnt[d];
  float acc[8] = {};
  for (int j0 = 0; j0 < cnt; j0 += 64) {
    int nn = cnt - j0; nn = nn < 64 ? nn : 64;
    int sl = (j0 + lane < cnt) ? c_sorted[start + j0 + lane] : 0;
    int jj = 0;
    for (; jj + 8 <= nn; jj += 8) {  // 4 pairs = 8 edges
      int ss[4]; uint4 vv[4];
#pragma unroll
      for (int u = 0; u < 4; ++u) ss[u] = __shfl(sl, jj + 2 * u + half);
#pragma unroll
      for (int u = 0; u < 4; ++u) vv[u] = base[(size_t)ss[u] * 32 + hl];
#pragma unroll
      for (int u = 0; u < 4; ++u) {
        const u16* p = (const u16*)&vv[u];
#pragma unroll
        for (int e = 0; e < 8; ++e) acc[e] += bf16f(p[e]);
      }
    }
    for (; jj < nn; jj += 2) {  // pair tail, weight-masked
      int idx = jj + half;
      int s = __shfl(sl, idx < nn ? idx : jj);
      float wgt = (idx < nn) ? 1.f : 0.f;
      uint4 v = base[(size_t)s * 32 + hl];
      const u16* p = (const u16*)&v;
#pragma unroll
      for (int e = 0; e < 8; ++e) acc[e] = fmaf(bf16f(p[e]), wgt, acc[e]);
    }
  }
  {
    uint4 v = base[(size_t)d * 32 + hl];
    float wgt = half ? 0.f : 1.f;   // self row added once
    const u16* p = (const u16*)&v;
#pragma unroll
    for (int e = 0; e < 8; ++e) acc[e] = fmaf(bf16f(p[e]), wgt, acc[e]);
  }
  float dd = dinv[d];
  float f[8];
#pragma unroll
  for (int e = 0; e < 8; ++e) f[e] = (acc[e] + __shfl_xor(acc[e], 32)) * dd;
  if (lane < 32) {
    uint4 O;
    O.x = pack2(f[0], f[1]); O.y = pack2(f[2], f[3]);
    O.z = pack2(f[4], f[5]); O.w = pack2(f[6], f[7]);
    ((uint4*)xout)[(size_t)d * 32 + hl] = O;
  }
}

// author mean: row = 256B = 16 uint4; 16 lanes cover a row; 4 edges/wave.
__device__ __forceinline__ void mean_body(
    const uint4* __restrict__ xa, const int* __restrict__ w_off,
    const int* __restrict__ w_cnt, const int* __restrict__ w_sorted,
    u16* __restrict__ mean, int d, int lane) {
  const int hl = lane & 15;
  const int qt = lane >> 4;
  int start = w_off[d], cnt = w_cnt[d];
  float acc[8] = {};
  for (int j0 = 0; j0 < cnt; j0 += 64) {
    int nn = cnt - j0; nn = nn < 64 ? nn : 64;
    int sl = (j0 + lane < cnt) ? w_sorted[start + j0 + lane] : 0;
    int jj = 0;
    for (; jj + 8 <= nn; jj += 8) {  // 2 quads = 8 edges
      int ss[2]; uint4 vv[2];
#pragma unroll
      for (int u = 0; u < 2; ++u) ss[u] = __shfl(sl, jj + 4 * u + qt);
#pragma unroll
      for (int u = 0; u < 2; ++u) vv[u] = xa[(size_t)ss[u] * 16 + hl];
#pragma unroll
      for (int u = 0; u < 2; ++u) {
        const u16* p = (const u16*)&vv[u];
#pragma unroll
        for (int e = 0; e < 8; ++e) acc[e] += bf16f(p[e]);
      }
    }
    for (; jj < nn; jj += 4) {  // quad tail, weight-masked
      int idx = jj + qt;
      int s = __shfl(sl, idx < nn ? idx : jj);
      float wgt = (idx < nn) ? 1.f : 0.f;
      uint4 v = xa[(size_t)s * 16 + hl];
      const u16* p = (const u16*)&v;
#pragma unroll
      for (int e = 0; e < 8; ++e) acc[e] = fmaf(bf16f(p[e]), wgt, acc[e]);
    }
  }
  float inv = 1.0f / (float)((cnt > 0) ? cnt : 1);
  float f[8];
#pragma unroll
  for (int e = 0; e < 8; ++e) {
    float x = acc[e] + __shfl_xor(acc[e], 16);
    x += __shfl_xor(x, 32);
    f[e] = x * inv;
  }
  if (lane < 16) {
    uint4 O;
    O.x = pack2(f[0], f[1]); O.y = pack2(f[2], f[3]);
    O.z = pack2(f[4], f[5]); O.w = pack2(f[6], f[7]);
    ((uint4*)mean)[(size_t)d * 16 + hl] = O;
  }
}

// -------- fused gather: blocks [0,nbw) = cites agg; [nbw,2*nbw) = author mean --
__global__ void gather_fused(
    const u16* __restrict__ xind, const float* __restrict__ dinv,
    const int* __restrict__ c_off, const int* __restrict__ c_cnt,
    const int* __restrict__ c_sorted, u16* __restrict__ xout,
    const u16* __restrict__ xa16, const int* __restrict__ w_off,
    const int* __restrict__ w_cnt, const int* __restrict__ w_sorted,
    u16* __restrict__ mean, int n, int nbw) {
  const int lane = threadIdx.x & 63;
  if (blockIdx.x < nbw) {
    int d = ((blockIdx.x * blockDim.x) >> 6) + (threadIdx.x >> 6);
    if (d >= n) return;
    agg_body((const uint4*)xind, dinv, c_off, c_cnt, c_sorted, xout, d, lane);
  } else {
    int d = (((blockIdx.x - nbw) * blockDim.x) >> 6) + (threadIdx.x >> 6);
    if (d >= n) return;
    mean_body((const uint4*)xa16, w_off, w_cnt, w_sorted, mean, d, lane);
  }
}

// ---------------- agg_gcn standalone (layer 2, reads pre-scaled pbd) ----------
__global__ void agg_gcn(const u16* __restrict__ xind, const float* __restrict__ dinv,
                        const int* __restrict__ c_off, const int* __restrict__ c_cnt,
                        const int* __restrict__ c_sorted,
                        u16* __restrict__ xout, int n) {
  int d = (blockIdx.x * blockDim.x + threadIdx.x) >> 6;
  int lane = threadIdx.x & 63;
  if (d >= n) return;
  agg_body((const uint4*)xind, dinv, c_off, c_cnt, c_sorted, xout, d, lane);
}

// ------------- bf16 MFMA GEMM: tile 128x128, 4 waves (2x2), 32KB LDS ----------
// NSEG=3: C = A0@B0 + A1@B1 + A2@B2(K=128) + bias -> relu -> bf16 [M][256]
//         optional Cpd = bf16(dinv[row]*relu(v)) dual write.
// NSEG=1: C = A0@B0 + bias -> f32 [M][N] (col-masked). NC col tiles of 128.
template <int NSEG, bool F32OUT, int NC>
__global__ __launch_bounds__(256, 4) void gemm_bf16(
    const u16* __restrict__ A0, const u16* __restrict__ A1, const u16* __restrict__ A2,
    const u16* __restrict__ B0, const u16* __restrict__ B1, const u16* __restrict__ B2,
    const float* __restrict__ bias, const float* __restrict__ dinv,
    u16* __restrict__ Cp, u16* __restrict__ Cpd, float* __restrict__ Cf,
    int M, int N) {
  __shared__ u16 Ah[2][4096];
  __shared__ u16 Bh[2][4096];

  const int t = threadIdx.x;
  const int wid = t >> 6, lane = t & 63;
  const int wr = wid >> 1, wc = wid & 1;
  const int lrow = lane & 15, kslot = lane >> 4;
  const int jsw = kslot ^ ((lrow >> 1) & 3);

  const int nb = gridDim.x;
  const int q = nb >> 3, r = nb & 7;
  const int xcd = blockIdx.x & 7, pos = blockIdx.x >> 3;
  const int lin = (xcd < r ? xcd * (q + 1) : r * (q + 1) + (xcd - r) * q) + pos;
  const int bx = lin / NC, by = lin - bx * NC;
  const int gm = bx * 128;
  const int gn = by * 128;

  const int s_r = lane >> 2;
  const int s_j = (lane & 3) ^ ((s_r >> 1) & 3);

  f32x4 acc[4][4];
  const f32x4 z4 = {0.f, 0.f, 0.f, 0.f};
#pragma unroll
  for (int m = 0; m < 4; ++m)
#pragma unroll
    for (int n = 0; n < 4; ++n) acc[m][n] = z4;

  const int NT = (NSEG == 3) ? 20 : 8;

  auto STAGE = [&](int tt, int half) {
    const u16* A;
    const u16* B;
    int rs, k0;
    if (NSEG == 3 && tt >= 16)     { A = A2; B = B2; rs = 128; k0 = (tt - 16) * 32; }
    else if (NSEG == 3 && tt >= 8) { A = A1; B = B1; rs = 256; k0 = (tt - 8) * 32; }
    else                           { A = A0; B = B0; rs = 256; k0 = tt * 32; }
    const int c = wid * 2;
#pragma unroll
    for (int cc = 0; cc < 2; ++cc) {
      int grow = gm + (c + cc) * 16 + s_r;
      grow = grow < M ? grow : M - 1;
      gload16(A + (size_t)grow * rs + (k0 + s_j * 8), &Ah[half][(c + cc) * 512]);
      int col = gn + (c + cc) * 16 + s_r;
      gload16(B + (size_t)col * rs + (k0 + s_j * 8), &Bh[half][(c + cc) * 512]);
    }
  };

  STAGE(0, 0);
  __syncthreads();

  for (int tt = 0; tt < NT; ++tt) {
    const int half = tt & 1;
    if (tt + 1 < NT) STAGE(tt + 1, half ^ 1);

    bf16x8 ah[4];
    const int ab = (wr * 64 + lrow) * 32 + jsw * 8;
#pragma unroll
    for (int m = 0; m < 4; ++m) ah[m] = *(const bf16x8*)&Ah[half][ab + m * 512];
    const int bb = (wc * 64 + lrow) * 32 + jsw * 8;
#pragma unroll
    for (int n = 0; n < 4; ++n) {
      bf16x8 bn = *(const bf16x8*)&Bh[half][bb + n * 512];
#pragma unroll
      for (int m = 0; m < 4; ++m)
        acc[m][n] = __builtin_amdgcn_mfma_f32_16x16x32_bf16(ah[m], bn, acc[m][n], 0, 0, 0);
    }
    __syncthreads();
  }

  const int col0 = gn + wc * 64 + lrow;
  const int row00 = gm + wr * 64 + kslot * 4;
#pragma unroll
  for (int m = 0; m < 4; ++m) {
#pragma unroll
    for (int i = 0; i < 4; ++i) {
      int row = row00 + m * 16 + i;
      if (row >= M) continue;
      float dv = (!F32OUT && Cpd) ? dinv[row] : 0.f;
#pragma unroll
      for (int n = 0; n < 4; ++n) {
        int col = col0 + n * 16;
        float v = acc[m][n][i] + bias[col];
        if (F32OUT) {
          if (col < N) Cf[(size_t)row * N + col] = v;
        } else {
          float rv = fmaxf(v, 0.f);
          Cp[(size_t)row * 256 + col] = bf16_rn(rv);
          if (Cpd) Cpd[(size_t)row * 256 + col] = bf16_rn(rv * dv);
        }
      }
    }
  }
}

// ---------------- launch ----------------
static inline size_t align_up(size_t x) { return (x + 255) & ~(size_t)255; }

extern "C" void kernel_launch(void* const* d_in, const int* in_sizes, int n_in,
                              void* d_out, int out_size, void* d_ws, size_t ws_size,
                              hipStream_t stream) {
  const float* x_paper  = (const float*)d_in[0];
  const float* x_author = (const float*)d_in[1];
  const int*   cites    = (const int*)d_in[2];
  const int*   w_src    = (const int*)d_in[3];
  const int*   w_dst    = (const int*)d_in[4];
  const float* W1  = (const float*)d_in[5];
  const float* b1  = (const float*)d_in[6];
  const float* Wl1 = (const float*)d_in[7];
  const float* bl1 = (const float*)d_in[8];
  const float* Wr1 = (const float*)d_in[9];
  const float* W2  = (const float*)d_in[10];
  const float* b2  = (const float*)d_in[11];
  const float* Wl2 = (const float*)d_in[12];
  const float* bl2 = (const float*)d_in[13];
  const float* Wr2 = (const float*)d_in[14];
  const float* linW = (const float*)d_in[15];
  const float* linb = (const float*)d_in[16];
  float* out = (float*)d_out;

  const int N = in_sizes[0] / DP;       // 100000
  const int NA = in_sizes[1] / DA;      // 50000
  const int E = in_sizes[3];            // 1000000
  const int* c_src = cites;
  const int* c_dst = cites + E;

  const int NCH = (E + CHUNK - 1) / CHUNK;       // 245
  const int NB = (N + 127) >> 7;                 // 782
  const int GC2 = 2 * NB * NCH;

  char* w = (char*)d_ws;
  size_t off = 0;
  auto alloc = [&](size_t bytes) -> void* {
    void* p = w + off;
    off = align_up(off + bytes);
    return p;
  };
  int* deg_c      = (int*)alloc((size_t)N * 4);
  int* cnt_w      = (int*)alloc((size_t)N * 4);
  int* cites_off  = (int*)alloc((size_t)N * 4);
  int* writes_off = (int*)alloc((size_t)N * 4);
  int* c_sorted   = (int*)alloc((size_t)E * 4);
  int* w_sorted   = (int*)alloc((size_t)E * 4);
  u32* tmpE       = (u32*)alloc((size_t)2 * NCH * CHUNK * 4);
  int* gcount     = (int*)alloc((size_t)GC2 * 4);
  int* gprefix    = (int*)alloc((size_t)GC2 * 4);
  int* lofs       = (int*)alloc((size_t)2 * NCH * NBKT * 4);
  int* bsumA      = (int*)alloc(256 * 4);
  float* dinv     = (float*)alloc((size_t)N * 4);
  u16* xa16       = (u16*)alloc((size_t)NA * DA * 2);
  u16* meanA      = (u16*)alloc((size_t)N * DA * 2);
  u16* xp         = (u16*)alloc((size_t)N * 256 * 2);
  u16* xpd        = (u16*)alloc((size_t)N * 256 * 2);
  u16* xs         = (u16*)alloc((size_t)N * 256 * 2);
  u16* pb         = (u16*)alloc((size_t)N * 256 * 2);
  u16* pbd        = (u16*)alloc((size_t)N * 256 * 2);
  const int bsW = 256 * 256, bsL = 256 * 128, bsLin = 384 * 256;
  u16* BtW1  = (u16*)alloc((size_t)bsW * 2);
  u16* BtWr1 = (u16*)alloc((size_t)bsW * 2);
  u16* BtW2  = (u16*)alloc((size_t)bsW * 2);
  u16* BtWr2 = (u16*)alloc((size_t)bsW * 2);
  u16* BtWl1 = (u16*)alloc((size_t)bsL * 2);
  u16* BtWl2 = (u16*)alloc((size_t)bsL * 2);
  u16* BtLin = (u16*)alloc((size_t)bsLin * 2);
  float* biasR1  = (float*)alloc(256 * 4);
  float* biasR2  = (float*)alloc(256 * 4);
  float* biasLin = (float*)alloc(384 * 4);
  (void)ws_size; (void)n_in; (void)out_size;

  const int nsb2 = (GC2 + SCAN_TILE - 1) / SCAN_TILE;

  // ---- fused CSR build (both edge types) ----
  sort_pass1<<<2 * NCH, 256, 0, stream>>>(c_src, c_dst, w_src, w_dst,
                                          tmpE, gcount, lofs, E, NCH);
  scan_local<<<nsb2, SCAN_TPB, 0, stream>>>(gcount, gprefix, bsumA, GC2);
  scan_spine<<<1, 256, 0, stream>>>(bsumA, nsb2);
  scan_add<<<nsb2, SCAN_TPB, 0, stream>>>(gprefix, bsumA, GC2);
  sort_pass2<<<2 * NB, 256, 0, stream>>>(tmpE, gprefix, gcount, lofs,
                                         c_sorted, deg_c, cites_off,
                                         w_sorted, cnt_w, writes_off,
                                         dinv, E, NCH, N, NB);

  // ---- fused prep (convs incl. scaled copy + weights + biases) ----
  {
    const int R1 = (N * 32 + 255) / 256;
    const int R2 = R1 + (NA * 16 + 255) / 256;
    const int total = R2 + 4 * 256 + 2 * 128 + 384 + 1;
    prep_all<<<total, 256, 0, stream>>>(
        x_paper, x_author, dinv, xp, xpd, xa16,
        W1, Wr1, W2, Wr2, Wl1, Wl2, linW,
        BtW1, BtWr1, BtW2, BtWr2, BtWl1, BtWl2, BtLin,
        b1, bl1, b2, bl2, linb, biasR1, biasR2, biasLin, N, NA);
  }

  const int nbWave = (N * 64 + 255) / 256;
  const int GX = (N + 127) / 128;  // 782

  // layer 1: fused agg(cites, xpd->xs) + author-mean
  gather_fused<<<2 * nbWave, 256, 0, stream>>>(
      xpd, dinv, cites_off, deg_c, c_sorted, xs,
      xa16, writes_off, cnt_w, w_sorted, meanA, N, nbWave);
  gemm_bf16<3, false, 2><<<GX * 2, 256, 0, stream>>>(
      xs, xp, meanA, BtW1, BtWr1, BtWl1, biasR1, dinv, pb, pbd, nullptr, N, HIDN);
  // layer 2
  agg_gcn<<<nbWave, 256, 0, stream>>>(pbd, dinv, cites_off, deg_c, c_sorted, xs, N);
  gemm_bf16<3, false, 2><<<GX * 2, 256, 0, stream>>>(
      xs, pb, meanA, BtW2, BtWr2, BtWl2, biasR2, nullptr, xp, nullptr, nullptr, N, HIDN);
  // output projection: 3 col tiles of 128 (384 >= 349)
  gemm_bf16<1, true, 3><<<GX * 3, 256, 0, stream>>>(
      xp, nullptr, nullptr, BtLin, nullptr, nullptr, biasLin, nullptr,
      nullptr, nullptr, out, N, DOUT);
}

// Round 12
// 461.611 us; speedup vs baseline: 1.1236x; 1.1236x over previous
//
#include <hip/hip_runtime.h>

// HeteroGNN on MI355X — round 12: revert to round-10 configuration (best: 461us).
// Round-11's pre-scaled-row experiment removed per-edge dinv (null on gather
// time) but added 100MB of writes (net -58us regression). This restores:
//   - per-edge dinv in agg_body (L2-resident, measured free)
//   - single xp plane, no xpd/pbd buffers
//   - wide-transaction gathers (2 edges/wave x 16B-lane), packed 4B sort,
//     fused prep, 128x128 4-wave MFMA GEMMs with XCD-chunked swizzle.

#define DP   256
#define DA   128
#define HIDN 256
#define DOUT 349
#define NBKT 782          // ceil(100000/128)
#define CHUNK 4096

typedef unsigned short u16;
typedef unsigned int u32;
typedef __attribute__((ext_vector_type(8))) short bf16x8;
typedef __attribute__((ext_vector_type(4))) float f32x4;

__device__ __forceinline__ u16 bf16_rn(float x) {
  union { float f; unsigned u; } v; v.f = x;
  unsigned r = v.u + 0x7FFFu + ((v.u >> 16) & 1u);
  return (u16)(r >> 16);
}
__device__ __forceinline__ float bf16f(u16 h) {
  union { float f; unsigned u; } v; v.u = ((unsigned)h) << 16; return v.f;
}
__device__ __forceinline__ unsigned pack2(float a, float b) {
  return (unsigned)bf16_rn(a) | ((unsigned)bf16_rn(b) << 16);
}

__device__ __forceinline__ void gload16(const void* g, void* lds) {
  __builtin_amdgcn_global_load_lds(
      (const __attribute__((address_space(1))) unsigned int*)g,
      (__attribute__((address_space(3))) unsigned int*)lds, 16, 0, 0);
}

// ---------------- exclusive scan (2048/block) ----------------
#define SCAN_TPB 256
#define SCAN_VPT 8
#define SCAN_TILE 2048

__global__ void scan_local(const int* __restrict__ in, int* __restrict__ out,
                           int* __restrict__ bsum, int n) {
  __shared__ int sdata[SCAN_TPB];
  int t = threadIdx.x;
  int base = blockIdx.x * SCAN_TILE + t * SCAN_VPT;
  int v[SCAN_VPT];
  int sum = 0;
#pragma unroll
  for (int j = 0; j < SCAN_VPT; ++j) {
    int idx = base + j;
    v[j] = (idx < n) ? in[idx] : 0;
    sum += v[j];
  }
  sdata[t] = sum;
  __syncthreads();
  for (int off = 1; off < SCAN_TPB; off <<= 1) {
    int x = (t >= off) ? sdata[t - off] : 0;
    __syncthreads();
    sdata[t] += x;
    __syncthreads();
  }
  int prefix = sdata[t] - sum;
  if (t == SCAN_TPB - 1) bsum[blockIdx.x] = sdata[t];
  int run = prefix;
#pragma unroll
  for (int j = 0; j < SCAN_VPT; ++j) {
    int idx = base + j;
    if (idx < n) out[idx] = run;
    run += v[j];
  }
}

__global__ void scan_spine(int* __restrict__ bsum, int nb) {
  __shared__ int sdata[256];
  int t = threadIdx.x;
  int v = (t < nb) ? bsum[t] : 0;
  sdata[t] = v;
  __syncthreads();
  for (int off = 1; off < 256; off <<= 1) {
    int x = (t >= off) ? sdata[t - off] : 0;
    __syncthreads();
    sdata[t] += x;
    __syncthreads();
  }
  if (t < nb) bsum[t] = sdata[t] - v;
}

__global__ void scan_add(int* __restrict__ out, const int* __restrict__ bsum, int n) {
  int add = bsum[blockIdx.x];
  int base = blockIdx.x * SCAN_TILE + threadIdx.x * SCAN_VPT;
#pragma unroll
  for (int j = 0; j < SCAN_VPT; ++j) {
    int idx = base + j;
    if (idx < n) out[idx] += add;
  }
}

// -------- sort pass 1 (both edge types): chunk -> bucketed packed tmp (u32) ----
__global__ __launch_bounds__(256) void sort_pass1(
    const int* __restrict__ c_src, const int* __restrict__ c_dst,
    const int* __restrict__ w_srcP, const int* __restrict__ w_dstP,
    u32* __restrict__ tmp, int* __restrict__ gcount, int* __restrict__ lofs,
    int E, int nch) {
  const int cg = blockIdx.x, t = threadIdx.x;
  const int et = cg >= nch;
  const int c = cg - et * nch;
  const int* src = et ? w_srcP : c_src;
  const int* dst = et ? w_dstP : c_dst;
  __shared__ u32 cnt[NBKT];
  __shared__ u32 ofs[NBKT];
  __shared__ u32 sdata[256];
  __shared__ u32 pay[CHUNK];
  __shared__ u16 bkt[CHUNK];

  for (int i = t; i < NBKT; i += 256) cnt[i] = 0;
  __syncthreads();
  const int base = c * CHUNK;
#pragma unroll
  for (int j = 0; j < 16; ++j) {
    int i = t + j * 256, idx = base + i;
    if (idx < E) {
      u32 s = (u32)src[idx], d = (u32)dst[idx];
      pay[i] = (s << 7) | (d & 127u);
      bkt[i] = (u16)(d >> 7);
      atomicAdd(&cnt[d >> 7], 1u);
    }
  }
  __syncthreads();
  for (int i = t; i < NBKT; i += 256)
    gcount[((size_t)et * NBKT + i) * nch + c] = (int)cnt[i];
  u32 ssum = 0;
  const int b0 = t * 4;
#pragma unroll
  for (int j = 0; j < 4; ++j) {
    int i = b0 + j;
    if (i < NBKT) ssum += cnt[i];
  }
  sdata[t] = ssum;
  __syncthreads();
  for (int o = 1; o < 256; o <<= 1) {
    u32 x = (t >= o) ? sdata[t - o] : 0;
    __syncthreads();
    sdata[t] += x;
    __syncthreads();
  }
  u32 run = sdata[t] - ssum;
#pragma unroll
  for (int j = 0; j < 4; ++j) {
    int i = b0 + j;
    if (i < NBKT) { ofs[i] = run; run += cnt[i]; }
  }
  __syncthreads();
  for (int i = t; i < NBKT; i += 256) {
    lofs[((size_t)et * nch + c) * NBKT + i] = (int)ofs[i];
    cnt[i] = ofs[i];
  }
  __syncthreads();
  u32* tout = tmp + (size_t)et * nch * CHUNK + base;
#pragma unroll
  for (int j = 0; j < 16; ++j) {
    int i = t + j * 256, idx = base + i;
    if (idx < E) {
      u32 p = atomicAdd(&cnt[bkt[i]], 1u);
      tout[p] = pay[i];
    }
  }
}

// -------- sort pass 2 (both edge types): bucket -> sorted + deg + off (+dinv) ---
#define MAXB 2560
__global__ __launch_bounds__(256) void sort_pass2(
    const u32* __restrict__ tmp, const int* __restrict__ prefix,
    const int* __restrict__ gcount, const int* __restrict__ lofs,
    int* __restrict__ cSorted, int* __restrict__ cDeg, int* __restrict__ cOff,
    int* __restrict__ wSorted, int* __restrict__ wDeg, int* __restrict__ wOff,
    float* __restrict__ dinv,
    int E, int nch, int n, int nbk) {
  const int bg = blockIdx.x, t = threadIdx.x;
  const int et = bg >= nbk;
  const int b = bg - et * nbk;
  int* outSorted = et ? wSorted : cSorted;
  int* deg = et ? wDeg : cDeg;
  int* offArr = et ? wOff : cOff;
  __shared__ u32 est[MAXB];
  __shared__ u32 outl[MAXB];
  __shared__ u32 cnt[128], ofs[128];
  __shared__ u32 sdata[256];

  const int node0 = b << 7;
  const size_t bgl = (size_t)et * NBKT + b;
  const int ebaseG = prefix[bgl * nch];
  const int eendG = (bg == 2 * nbk - 1) ? 2 * E : prefix[(bgl + 1) * nch];
  const int ebase = ebaseG - et * E;
  const int esize = (eendG - et * E) - ebase;

  const u32* tsrc = tmp + (size_t)et * nch * CHUNK;
  for (int c = t; c < nch; c += 256) {
    int g = lofs[((size_t)et * nch + c) * NBKT + b];
    int len = gcount[bgl * nch + c];
    int dp = prefix[bgl * nch + c] - ebaseG;
    for (int k = 0; k < len; ++k)
      est[dp + k] = tsrc[(size_t)c * CHUNK + g + k];
  }
  if (t < 128) cnt[t] = 0;
  __syncthreads();
  for (int i = t; i < esize; i += 256) atomicAdd(&cnt[est[i] & 127u], 1u);
  __syncthreads();
  u32 v = (t < 128) ? cnt[t] : 0;
  sdata[t] = v;
  __syncthreads();
  for (int o = 1; o < 256; o <<= 1) {
    u32 x = (t >= o) ? sdata[t - o] : 0;
    __syncthreads();
    sdata[t] += x;
    __syncthreads();
  }
  if (t < 128) ofs[t] = sdata[t] - v;
  __syncthreads();
  const int nNodes = (n - node0) < 128 ? (n - node0) : 128;
  if (t < nNodes) {
    deg[node0 + t] = (int)cnt[t];
    offArr[node0 + t] = ebase + (int)ofs[t];
    if (et == 0) dinv[node0 + t] = rsqrtf((float)(cnt[t] + 1));
  }
  __syncthreads();
  if (t < 128) cnt[t] = ofs[t];
  __syncthreads();
  for (int i = t; i < esize; i += 256) {
    u32 e = est[i];
    u32 p = atomicAdd(&cnt[e & 127u], 1u);
    outl[p] = e >> 7;
  }
  __syncthreads();
  for (int i = t; i < esize; i += 256) outSorted[ebase + i] = (int)outl[i];
}

// ---------------- fused prep: convs + weight transposes + biases ----------------
__global__ void prep_all(
    const float* __restrict__ x_paper, const float* __restrict__ x_author,
    u16* __restrict__ xp, u16* __restrict__ xa16,
    const float* __restrict__ W1, const float* __restrict__ Wr1,
    const float* __restrict__ W2, const float* __restrict__ Wr2,
    const float* __restrict__ Wl1, const float* __restrict__ Wl2,
    const float* __restrict__ linW,
    u16* __restrict__ BtW1, u16* __restrict__ BtWr1,
    u16* __restrict__ BtW2, u16* __restrict__ BtWr2,
    u16* __restrict__ BtWl1, u16* __restrict__ BtWl2, u16* __restrict__ BtLin,
    const float* __restrict__ b1, const float* __restrict__ bl1,
    const float* __restrict__ b2, const float* __restrict__ bl2,
    const float* __restrict__ linb,
    float* __restrict__ biasR1, float* __restrict__ biasR2,
    float* __restrict__ biasLin,
    int N, int NA) {
  const int R1 = (N * 32 + 255) / 256;
  const int R2 = R1 + (NA * 16 + 255) / 256;
  const int WB = 256 * 256 / 256;
  const int LB = 256 * 128 / 256;
  const int FB = 384 * 256 / 256;
  int bid = blockIdx.x, t = threadIdx.x;

  if (bid < R1) {
    int i = bid * 256 + t;
    if (i < N * 32) {
      const float4* x4 = (const float4*)x_paper;
      float4 v0 = x4[(size_t)i * 2];
      float4 v1 = x4[(size_t)i * 2 + 1];
      uint4 O;
      O.x = pack2(v0.x, v0.y); O.y = pack2(v0.z, v0.w);
      O.z = pack2(v1.x, v1.y); O.w = pack2(v1.z, v1.w);
      ((uint4*)xp)[i] = O;
    }
    return;
  }
  if (bid < R2) {
    int i = (bid - R1) * 256 + t;
    if (i < NA * 16) {
      const float4* x4 = (const float4*)x_author;
      float4 v0 = x4[(size_t)i * 2];
      float4 v1 = x4[(size_t)i * 2 + 1];
      uint4 O;
      O.x = pack2(v0.x, v0.y); O.y = pack2(v0.z, v0.w);
      O.z = pack2(v1.x, v1.y); O.w = pack2(v1.z, v1.w);
      ((uint4*)xa16)[i] = O;
    }
    return;
  }
  int wb = bid - R2;
  const float* W; u16* Bt; int K, Nn, Npad;
  if      (wb < WB)                  { W = W1;  Bt = BtW1;  K = 256; Nn = 256; Npad = 256; }
  else if ((wb -= WB) < WB)          { W = Wr1; Bt = BtWr1; K = 256; Nn = 256; Npad = 256; }
  else if ((wb -= WB) < WB)          { W = W2;  Bt = BtW2;  K = 256; Nn = 256; Npad = 256; }
  else if ((wb -= WB) < WB)          { W = Wr2; Bt = BtWr2; K = 256; Nn = 256; Npad = 256; }
  else if ((wb -= WB) < LB)          { W = Wl1; Bt = BtWl1; K = 128; Nn = 256; Npad = 256; }
  else if ((wb -= LB) < LB)          { W = Wl2; Bt = BtWl2; K = 128; Nn = 256; Npad = 256; }
  else if ((wb -= LB) < FB)          { W = linW; Bt = BtLin; K = 256; Nn = DOUT; Npad = 384; }
  else {
    if (t < 256) {
      biasR1[t] = b1[t] + bl1[t];
      biasR2[t] = b2[t] + bl2[t];
    }
    for (int i = t; i < 384; i += 256) biasLin[i] = (i < DOUT) ? linb[i] : 0.f;
    return;
  }
  int idx = wb * 256 + t;
  int tot = Npad * K;
  if (idx >= tot) return;
  int nn = idx / K, k = idx - nn * K;
  float v = (nn < Nn) ? W[(size_t)k * Nn + nn] : 0.f;
  Bt[idx] = bf16_rn(v);
}

// ---- wide gather bodies -------------------------------------------------------
// cites agg: row = 512B = 32 uint4; 32 lanes cover a row; 2 edges/wave (halves).
__device__ __forceinline__ void agg_body(
    const uint4* __restrict__ base, const float* __restrict__ dinv,
    const int* __restrict__ c_off, const int* __restrict__ c_cnt,
    const int* __restrict__ c_sorted, u16* __restrict__ xout,
    int d, int lane) {
  const int hl = lane & 31;
  const int half = lane >> 5;
  int start = c_off[d], cnt = c_cnt[d];
  float acc[8] = {};
  for (int j0 = 0; j0 < cnt; j0 += 64) {
    int nn = cnt - j0; nn = nn < 64 ? nn : 64;
    int sl = (j0 + lane < cnt) ? c_sorted[start + j0 + lane] : 0;
    int jj = 0;
    for (; jj + 8 <= nn; jj += 8) {  // 4 pairs = 8 edges
      int ss[4]; float dv[4]; uint4 vv[4];
#pragma unroll
      for (int u = 0; u < 4; ++u) ss[u] = __shfl(sl, jj + 2 * u + half);
#pragma unroll
      for (int u = 0; u < 4; ++u) dv[u] = dinv[ss[u]];
#pragma unroll
      for (int u = 0; u < 4; ++u) vv[u] = base[(size_t)ss[u] * 32 + hl];
#pragma unroll
      for (int u = 0; u < 4; ++u) {
        const u16* p = (const u16*)&vv[u];
#pragma unroll
        for (int e = 0; e < 8; ++e) acc[e] = fmaf(bf16f(p[e]), dv[u], acc[e]);
      }
    }
    for (; jj < nn; jj += 2) {  // pair tail, weight-masked
      int idx = jj + half;
      int s = __shfl(sl, idx < nn ? idx : jj);
      float wgt = (idx < nn) ? dinv[s] : 0.f;
      uint4 v = base[(size_t)s * 32 + hl];
      const u16* p = (const u16*)&v;
#pragma unroll
      for (int e = 0; e < 8; ++e) acc[e] = fmaf(bf16f(p[e]), wgt, acc[e]);
    }
  }
  float dd = dinv[d];
  {
    uint4 v = base[(size_t)d * 32 + hl];
    float wgt = half ? 0.f : dd;   // self row added once
    const u16* p = (const u16*)&v;
#pragma unroll
    for (int e = 0; e < 8; ++e) acc[e] = fmaf(bf16f(p[e]), wgt, acc[e]);
  }
  float f[8];
#pragma unroll
  for (int e = 0; e < 8; ++e) f[e] = (acc[e] + __shfl_xor(acc[e], 32)) * dd;
  if (lane < 32) {
    uint4 O;
    O.x = pack2(f[0], f[1]); O.y = pack2(f[2], f[3]);
    O.z = pack2(f[4], f[5]); O.w = pack2(f[6], f[7]);
    ((uint4*)xout)[(size_t)d * 32 + hl] = O;
  }
}

// author mean: row = 256B = 16 uint4; 16 lanes cover a row; 4 edges/wave.
__device__ __forceinline__ void mean_body(
    const uint4* __restrict__ xa, const int* __restrict__ w_off,
    const int* __restrict__ w_cnt, const int* __restrict__ w_sorted,
    u16* __restrict__ mean, int d, int lane) {
  const int hl = lane & 15;
  const int qt = lane >> 4;
  int start = w_off[d], cnt = w_cnt[d];
  float acc[8] = {};
  for (int j0 = 0; j0 < cnt; j0 += 64) {
    int nn = cnt - j0; nn = nn < 64 ? nn : 64;
    int sl = (j0 + lane < cnt) ? w_sorted[start + j0 + lane] : 0;
    int jj = 0;
    for (; jj + 8 <= nn; jj += 8) {  // 2 quads = 8 edges
      int ss[2]; uint4 vv[2];
#pragma unroll
      for (int u = 0; u < 2; ++u) ss[u] = __shfl(sl, jj + 4 * u + qt);
#pragma unroll
      for (int u = 0; u < 2; ++u) vv[u] = xa[(size_t)ss[u] * 16 + hl];
#pragma unroll
      for (int u = 0; u < 2; ++u) {
        const u16* p = (const u16*)&vv[u];
#pragma unroll
        for (int e = 0; e < 8; ++e) acc[e] += bf16f(p[e]);
      }
    }
    for (; jj < nn; jj += 4) {  // quad tail, weight-masked
      int idx = jj + qt;
      int s = __shfl(sl, idx < nn ? idx : jj);
      float wgt = (idx < nn) ? 1.f : 0.f;
      uint4 v = xa[(size_t)s * 16 + hl];
      const u16* p = (const u16*)&v;
#pragma unroll
      for (int e = 0; e < 8; ++e) acc[e] = fmaf(bf16f(p[e]), wgt, acc[e]);
    }
  }
  float inv = 1.0f / (float)((cnt > 0) ? cnt : 1);
  float f[8];
#pragma unroll
  for (int e = 0; e < 8; ++e) {
    float x = acc[e] + __shfl_xor(acc[e], 16);
    x += __shfl_xor(x, 32);
    f[e] = x * inv;
  }
  if (lane < 16) {
    uint4 O;
    O.x = pack2(f[0], f[1]); O.y = pack2(f[2], f[3]);
    O.z = pack2(f[4], f[5]); O.w = pack2(f[6], f[7]);
    ((uint4*)mean)[(size_t)d * 16 + hl] = O;
  }
}

// -------- fused gather: blocks [0,nbw) = cites agg; [nbw,2*nbw) = author mean --
__global__ void gather_fused(
    const u16* __restrict__ xin, const float* __restrict__ dinv,
    const int* __restrict__ c_off, const int* __restrict__ c_cnt,
    const int* __restrict__ c_sorted, u16* __restrict__ xout,
    const u16* __restrict__ xa16, const int* __restrict__ w_off,
    const int* __restrict__ w_cnt, const int* __restrict__ w_sorted,
    u16* __restrict__ mean, int n, int nbw) {
  const int lane = threadIdx.x & 63;
  if (blockIdx.x < nbw) {
    int d = ((blockIdx.x * blockDim.x) >> 6) + (threadIdx.x >> 6);
    if (d >= n) return;
    agg_body((const uint4*)xin, dinv, c_off, c_cnt, c_sorted, xout, d, lane);
  } else {
    int d = (((blockIdx.x - nbw) * blockDim.x) >> 6) + (threadIdx.x >> 6);
    if (d >= n) return;
    mean_body((const uint4*)xa16, w_off, w_cnt, w_sorted, mean, d, lane);
  }
}

// ---------------- agg_gcn standalone (layer 2) ----------------
__global__ void agg_gcn(const u16* __restrict__ xin, const float* __restrict__ dinv,
                        const int* __restrict__ c_off, const int* __restrict__ c_cnt,
                        const int* __restrict__ c_sorted,
                        u16* __restrict__ xout, int n) {
  int d = (blockIdx.x * blockDim.x + threadIdx.x) >> 6;
  int lane = threadIdx.x & 63;
  if (d >= n) return;
  agg_body((const uint4*)xin, dinv, c_off, c_cnt, c_sorted, xout, d, lane);
}

// ------------- bf16 MFMA GEMM: tile 128x128, 4 waves (2x2), 32KB LDS ----------
template <int NSEG, bool F32OUT, int NC>
__global__ __launch_bounds__(256, 4) void gemm_bf16(
    const u16* __restrict__ A0, const u16* __restrict__ A1, const u16* __restrict__ A2,
    const u16* __restrict__ B0, const u16* __restrict__ B1, const u16* __restrict__ B2,
    const float* __restrict__ bias,
    u16* __restrict__ Cp, float* __restrict__ Cf,
    int M, int N) {
  __shared__ u16 Ah[2][4096];
  __shared__ u16 Bh[2][4096];

  const int t = threadIdx.x;
  const int wid = t >> 6, lane = t & 63;
  const int wr = wid >> 1, wc = wid & 1;
  const int lrow = lane & 15, kslot = lane >> 4;
  const int jsw = kslot ^ ((lrow >> 1) & 3);

  const int nb = gridDim.x;
  const int q = nb >> 3, r = nb & 7;
  const int xcd = blockIdx.x & 7, pos = blockIdx.x >> 3;
  const int lin = (xcd < r ? xcd * (q + 1) : r * (q + 1) + (xcd - r) * q) + pos;
  const int bx = lin / NC, by = lin - bx * NC;
  const int gm = bx * 128;
  const int gn = by * 128;

  const int s_r = lane >> 2;
  const int s_j = (lane & 3) ^ ((s_r >> 1) & 3);

  f32x4 acc[4][4];
  const f32x4 z4 = {0.f, 0.f, 0.f, 0.f};
#pragma unroll
  for (int m = 0; m < 4; ++m)
#pragma unroll
    for (int n = 0; n < 4; ++n) acc[m][n] = z4;

  const int NT = (NSEG == 3) ? 20 : 8;

  auto STAGE = [&](int tt, int half) {
    const u16* A;
    const u16* B;
    int rs, k0;
    if (NSEG == 3 && tt >= 16)     { A = A2; B = B2; rs = 128; k0 = (tt - 16) * 32; }
    else if (NSEG == 3 && tt >= 8) { A = A1; B = B1; rs = 256; k0 = (tt - 8) * 32; }
    else                           { A = A0; B = B0; rs = 256; k0 = tt * 32; }
    const int c = wid * 2;
#pragma unroll
    for (int cc = 0; cc < 2; ++cc) {
      int grow = gm + (c + cc) * 16 + s_r;
      grow = grow < M ? grow : M - 1;
      gload16(A + (size_t)grow * rs + (k0 + s_j * 8), &Ah[half][(c + cc) * 512]);
      int col = gn + (c + cc) * 16 + s_r;
      gload16(B + (size_t)col * rs + (k0 + s_j * 8), &Bh[half][(c + cc) * 512]);
    }
  };

  STAGE(0, 0);
  __syncthreads();

  for (int tt = 0; tt < NT; ++tt) {
    const int half = tt & 1;
    if (tt + 1 < NT) STAGE(tt + 1, half ^ 1);

    bf16x8 ah[4];
    const int ab = (wr * 64 + lrow) * 32 + jsw * 8;
#pragma unroll
    for (int m = 0; m < 4; ++m) ah[m] = *(const bf16x8*)&Ah[half][ab + m * 512];
    const int bb = (wc * 64 + lrow) * 32 + jsw * 8;
#pragma unroll
    for (int n = 0; n < 4; ++n) {
      bf16x8 bn = *(const bf16x8*)&Bh[half][bb + n * 512];
#pragma unroll
      for (int m = 0; m < 4; ++m)
        acc[m][n] = __builtin_amdgcn_mfma_f32_16x16x32_bf16(ah[m], bn, acc[m][n], 0, 0, 0);
    }
    __syncthreads();
  }

  const int col0 = gn + wc * 64 + lrow;
  const int row00 = gm + wr * 64 + kslot * 4;
#pragma unroll
  for (int m = 0; m < 4; ++m) {
#pragma unroll
    for (int i = 0; i < 4; ++i) {
      int row = row00 + m * 16 + i;
      if (row >= M) continue;
#pragma unroll
      for (int n = 0; n < 4; ++n) {
        int col = col0 + n * 16;
        float v = acc[m][n][i] + bias[col];
        if (F32OUT) {
          if (col < N) Cf[(size_t)row * N + col] = v;
        } else {
          Cp[(size_t)row * 256 + col] = bf16_rn(fmaxf(v, 0.f));
        }
      }
    }
  }
}

// ---------------- launch ----------------
static inline size_t align_up(size_t x) { return (x + 255) & ~(size_t)255; }

extern "C" void kernel_launch(void* const* d_in, const int* in_sizes, int n_in,
                              void* d_out, int out_size, void* d_ws, size_t ws_size,
                              hipStream_t stream) {
  const float* x_paper  = (const float*)d_in[0];
  const float* x_author = (const float*)d_in[1];
  const int*   cites    = (const int*)d_in[2];
  const int*   w_src    = (const int*)d_in[3];
  const int*   w_dst    = (const int*)d_in[4];
  const float* W1  = (const float*)d_in[5];
  const float* b1  = (const float*)d_in[6];
  const float* Wl1 = (const float*)d_in[7];
  const float* bl1 = (const float*)d_in[8];
  const float* Wr1 = (const float*)d_in[9];
  const float* W2  = (const float*)d_in[10];
  const float* b2  = (const float*)d_in[11];
  const float* Wl2 = (const float*)d_in[12];
  const float* bl2 = (const float*)d_in[13];
  const float* Wr2 = (const float*)d_in[14];
  const float* linW = (const float*)d_in[15];
  const float* linb = (const float*)d_in[16];
  float* out = (float*)d_out;

  const int N = in_sizes[0] / DP;       // 100000
  const int NA = in_sizes[1] / DA;      // 50000
  const int E = in_sizes[3];            // 1000000
  const int* c_src = cites;
  const int* c_dst = cites + E;

  const int NCH = (E + CHUNK - 1) / CHUNK;       // 245
  const int NB = (N + 127) >> 7;                 // 782
  const int GC2 = 2 * NB * NCH;

  char* w = (char*)d_ws;
  size_t off = 0;
  auto alloc = [&](size_t bytes) -> void* {
    void* p = w + off;
    off = align_up(off + bytes);
    return p;
  };
  int* deg_c      = (int*)alloc((size_t)N * 4);
  int* cnt_w      = (int*)alloc((size_t)N * 4);
  int* cites_off  = (int*)alloc((size_t)N * 4);
  int* writes_off = (int*)alloc((size_t)N * 4);
  int* c_sorted   = (int*)alloc((size_t)E * 4);
  int* w_sorted   = (int*)alloc((size_t)E * 4);
  u32* tmpE       = (u32*)alloc((size_t)2 * NCH * CHUNK * 4);
  int* gcount     = (int*)alloc((size_t)GC2 * 4);
  int* gprefix    = (int*)alloc((size_t)GC2 * 4);
  int* lofs       = (int*)alloc((size_t)2 * NCH * NBKT * 4);
  int* bsumA      = (int*)alloc(256 * 4);
  float* dinv     = (float*)alloc((size_t)N * 4);
  u16* xa16       = (u16*)alloc((size_t)NA * DA * 2);
  u16* meanA      = (u16*)alloc((size_t)N * DA * 2);
  u16* xp         = (u16*)alloc((size_t)N * 256 * 2);
  u16* xs         = (u16*)alloc((size_t)N * 256 * 2);
  u16* pb         = (u16*)alloc((size_t)N * 256 * 2);
  const int bsW = 256 * 256, bsL = 256 * 128, bsLin = 384 * 256;
  u16* BtW1  = (u16*)alloc((size_t)bsW * 2);
  u16* BtWr1 = (u16*)alloc((size_t)bsW * 2);
  u16* BtW2  = (u16*)alloc((size_t)bsW * 2);
  u16* BtWr2 = (u16*)alloc((size_t)bsW * 2);
  u16* BtWl1 = (u16*)alloc((size_t)bsL * 2);
  u16* BtWl2 = (u16*)alloc((size_t)bsL * 2);
  u16* BtLin = (u16*)alloc((size_t)bsLin * 2);
  float* biasR1  = (float*)alloc(256 * 4);
  float* biasR2  = (float*)alloc(256 * 4);
  float* biasLin = (float*)alloc(384 * 4);
  (void)ws_size; (void)n_in; (void)out_size;

  const int nsb2 = (GC2 + SCAN_TILE - 1) / SCAN_TILE;

  // ---- fused CSR build (both edge types) ----
  sort_pass1<<<2 * NCH, 256, 0, stream>>>(c_src, c_dst, w_src, w_dst,
                                          tmpE, gcount, lofs, E, NCH);
  scan_local<<<nsb2, SCAN_TPB, 0, stream>>>(gcount, gprefix, bsumA, GC2);
  scan_spine<<<1, 256, 0, stream>>>(bsumA, nsb2);
  scan_add<<<nsb2, SCAN_TPB, 0, stream>>>(gprefix, bsumA, GC2);
  sort_pass2<<<2 * NB, 256, 0, stream>>>(tmpE, gprefix, gcount, lofs,
                                         c_sorted, deg_c, cites_off,
                                         w_sorted, cnt_w, writes_off,
                                         dinv, E, NCH, N, NB);

  // ---- fused prep (convs + weights + biases) ----
  {
    const int R1 = (N * 32 + 255) / 256;
    const int R2 = R1 + (NA * 16 + 255) / 256;
    const int total = R2 + 4 * 256 + 2 * 128 + 384 + 1;
    prep_all<<<total, 256, 0, stream>>>(
        x_paper, x_author, xp, xa16,
        W1, Wr1, W2, Wr2, Wl1, Wl2, linW,
        BtW1, BtWr1, BtW2, BtWr2, BtWl1, BtWl2, BtLin,
        b1, bl1, b2, bl2, linb, biasR1, biasR2, biasLin, N, NA);
  }

  const int nbWave = (N * 64 + 255) / 256;
  const int GX = (N + 127) / 128;  // 782

  // layer 1: fused agg(cites) + author-mean
  gather_fused<<<2 * nbWave, 256, 0, stream>>>(
      xp, dinv, cites_off, deg_c, c_sorted, xs,
      xa16, writes_off, cnt_w, w_sorted, meanA, N, nbWave);
  gemm_bf16<3, false, 2><<<GX * 2, 256, 0, stream>>>(
      xs, xp, meanA, BtW1, BtWr1, BtWl1, biasR1, pb, nullptr, N, HIDN);
  // layer 2
  agg_gcn<<<nbWave, 256, 0, stream>>>(pb, dinv, cites_off, deg_c, c_sorted, xs, N);
  gemm_bf16<3, false, 2><<<GX * 2, 256, 0, stream>>>(
      xs, pb, meanA, BtW2, BtWr2, BtWl2, biasR2, xp, nullptr, N, HIDN);
  // output projection: 3 col tiles of 128 (384 >= 349)
  gemm_bf16<1, true, 3><<<GX * 3, 256, 0, stream>>>(
      xp, nullptr, nullptr, BtLin, nullptr, nullptr, biasLin, nullptr, out, N, DOUT);
}

// Round 13
// 450.496 us; speedup vs baseline: 1.1514x; 1.0247x over previous
//
#include <hip/hip_runtime.h>

// HeteroGNN on MI355X — round 13: round-12 config + sort_pass1/prep_all fusion
// (independent dataflow tracks co-scheduled in one launch; sort's 490
// latency-bound blocks hide under prep's ~17k streaming blocks).

#define DP   256
#define DA   128
#define HIDN 256
#define DOUT 349
#define NBKT 782          // ceil(100000/128)
#define CHUNK 4096

typedef unsigned short u16;
typedef unsigned int u32;
typedef __attribute__((ext_vector_type(8))) short bf16x8;
typedef __attribute__((ext_vector_type(4))) float f32x4;

__device__ __forceinline__ u16 bf16_rn(float x) {
  union { float f; unsigned u; } v; v.f = x;
  unsigned r = v.u + 0x7FFFu + ((v.u >> 16) & 1u);
  return (u16)(r >> 16);
}
__device__ __forceinline__ float bf16f(u16 h) {
  union { float f; unsigned u; } v; v.u = ((unsigned)h) << 16; return v.f;
}
__device__ __forceinline__ unsigned pack2(float a, float b) {
  return (unsigned)bf16_rn(a) | ((unsigned)bf16_rn(b) << 16);
}

__device__ __forceinline__ void gload16(const void* g, void* lds) {
  __builtin_amdgcn_global_load_lds(
      (const __attribute__((address_space(1))) unsigned int*)g,
      (__attribute__((address_space(3))) unsigned int*)lds, 16, 0, 0);
}

// ---------------- exclusive scan (2048/block) ----------------
#define SCAN_TPB 256
#define SCAN_VPT 8
#define SCAN_TILE 2048

__global__ void scan_local(const int* __restrict__ in, int* __restrict__ out,
                           int* __restrict__ bsum, int n) {
  __shared__ int sdata[SCAN_TPB];
  int t = threadIdx.x;
  int base = blockIdx.x * SCAN_TILE + t * SCAN_VPT;
  int v[SCAN_VPT];
  int sum = 0;
#pragma unroll
  for (int j = 0; j < SCAN_VPT; ++j) {
    int idx = base + j;
    v[j] = (idx < n) ? in[idx] : 0;
    sum += v[j];
  }
  sdata[t] = sum;
  __syncthreads();
  for (int off = 1; off < SCAN_TPB; off <<= 1) {
    int x = (t >= off) ? sdata[t - off] : 0;
    __syncthreads();
    sdata[t] += x;
    __syncthreads();
  }
  int prefix = sdata[t] - sum;
  if (t == SCAN_TPB - 1) bsum[blockIdx.x] = sdata[t];
  int run = prefix;
#pragma unroll
  for (int j = 0; j < SCAN_VPT; ++j) {
    int idx = base + j;
    if (idx < n) out[idx] = run;
    run += v[j];
  }
}

__global__ void scan_spine(int* __restrict__ bsum, int nb) {
  __shared__ int sdata[256];
  int t = threadIdx.x;
  int v = (t < nb) ? bsum[t] : 0;
  sdata[t] = v;
  __syncthreads();
  for (int off = 1; off < 256; off <<= 1) {
    int x = (t >= off) ? sdata[t - off] : 0;
    __syncthreads();
    sdata[t] += x;
    __syncthreads();
  }
  if (t < nb) bsum[t] = sdata[t] - v;
}

__global__ void scan_add(int* __restrict__ out, const int* __restrict__ bsum, int n) {
  int add = bsum[blockIdx.x];
  int base = blockIdx.x * SCAN_TILE + threadIdx.x * SCAN_VPT;
#pragma unroll
  for (int j = 0; j < SCAN_VPT; ++j) {
    int idx = base + j;
    if (idx < n) out[idx] += add;
  }
}

// ---- fused sort pass 1 + prep: blocks [0,2*nch) sort, rest conv/weights -------
__global__ __launch_bounds__(256) void sort1_prep(
    const int* __restrict__ c_src, const int* __restrict__ c_dst,
    const int* __restrict__ w_srcP, const int* __restrict__ w_dstP,
    u32* __restrict__ tmp, int* __restrict__ gcount, int* __restrict__ lofs,
    int E, int nch,
    const float* __restrict__ x_paper, const float* __restrict__ x_author,
    u16* __restrict__ xp, u16* __restrict__ xa16,
    const float* __restrict__ W1, const float* __restrict__ Wr1,
    const float* __restrict__ W2, const float* __restrict__ Wr2,
    const float* __restrict__ Wl1, const float* __restrict__ Wl2,
    const float* __restrict__ linW,
    u16* __restrict__ BtW1, u16* __restrict__ BtWr1,
    u16* __restrict__ BtW2, u16* __restrict__ BtWr2,
    u16* __restrict__ BtWl1, u16* __restrict__ BtWl2, u16* __restrict__ BtLin,
    const float* __restrict__ b1, const float* __restrict__ bl1,
    const float* __restrict__ b2, const float* __restrict__ bl2,
    const float* __restrict__ linb,
    float* __restrict__ biasR1, float* __restrict__ biasR2,
    float* __restrict__ biasLin,
    int N, int NA) {
  __shared__ u32 cnt[NBKT];
  __shared__ u32 ofs[NBKT];
  __shared__ u32 sdata[256];
  __shared__ u32 pay[CHUNK];
  __shared__ u16 bkt[CHUNK];
  const int t = threadIdx.x;

  if (blockIdx.x < (unsigned)(2 * nch)) {
    // ---------------- sort pass 1 ----------------
    const int cg = blockIdx.x;
    const int et = cg >= nch;
    const int c = cg - et * nch;
    const int* src = et ? w_srcP : c_src;
    const int* dst = et ? w_dstP : c_dst;

    for (int i = t; i < NBKT; i += 256) cnt[i] = 0;
    __syncthreads();
    const int base = c * CHUNK;
#pragma unroll
    for (int j = 0; j < 16; ++j) {
      int i = t + j * 256, idx = base + i;
      if (idx < E) {
        u32 s = (u32)src[idx], d = (u32)dst[idx];
        pay[i] = (s << 7) | (d & 127u);
        bkt[i] = (u16)(d >> 7);
        atomicAdd(&cnt[d >> 7], 1u);
      }
    }
    __syncthreads();
    for (int i = t; i < NBKT; i += 256)
      gcount[((size_t)et * NBKT + i) * nch + c] = (int)cnt[i];
    u32 ssum = 0;
    const int b0 = t * 4;
#pragma unroll
    for (int j = 0; j < 4; ++j) {
      int i = b0 + j;
      if (i < NBKT) ssum += cnt[i];
    }
    sdata[t] = ssum;
    __syncthreads();
    for (int o = 1; o < 256; o <<= 1) {
      u32 x = (t >= o) ? sdata[t - o] : 0;
      __syncthreads();
      sdata[t] += x;
      __syncthreads();
    }
    u32 run = sdata[t] - ssum;
#pragma unroll
    for (int j = 0; j < 4; ++j) {
      int i = b0 + j;
      if (i < NBKT) { ofs[i] = run; run += cnt[i]; }
    }
    __syncthreads();
    for (int i = t; i < NBKT; i += 256) {
      lofs[((size_t)et * nch + c) * NBKT + i] = (int)ofs[i];
      cnt[i] = ofs[i];
    }
    __syncthreads();
    u32* tout = tmp + (size_t)et * nch * CHUNK + base;
#pragma unroll
    for (int j = 0; j < 16; ++j) {
      int i = t + j * 256, idx = base + i;
      if (idx < E) {
        u32 p = atomicAdd(&cnt[bkt[i]], 1u);
        tout[p] = pay[i];
      }
    }
    return;
  }

  // ---------------- prep (conv + weights + biases) ----------------
  const int R1 = (N * 32 + 255) / 256;
  const int R2 = R1 + (NA * 16 + 255) / 256;
  const int WB = 256 * 256 / 256;
  const int LB = 256 * 128 / 256;
  const int FB = 384 * 256 / 256;
  int bid = blockIdx.x - 2 * nch;

  if (bid < R1) {
    int i = bid * 256 + t;
    if (i < N * 32) {
      const float4* x4 = (const float4*)x_paper;
      float4 v0 = x4[(size_t)i * 2];
      float4 v1 = x4[(size_t)i * 2 + 1];
      uint4 O;
      O.x = pack2(v0.x, v0.y); O.y = pack2(v0.z, v0.w);
      O.z = pack2(v1.x, v1.y); O.w = pack2(v1.z, v1.w);
      ((uint4*)xp)[i] = O;
    }
    return;
  }
  if (bid < R2) {
    int i = (bid - R1) * 256 + t;
    if (i < NA * 16) {
      const float4* x4 = (const float4*)x_author;
      float4 v0 = x4[(size_t)i * 2];
      float4 v1 = x4[(size_t)i * 2 + 1];
      uint4 O;
      O.x = pack2(v0.x, v0.y); O.y = pack2(v0.z, v0.w);
      O.z = pack2(v1.x, v1.y); O.w = pack2(v1.z, v1.w);
      ((uint4*)xa16)[i] = O;
    }
    return;
  }
  int wb = bid - R2;
  const float* W; u16* Bt; int K, Nn, Npad;
  if      (wb < WB)                  { W = W1;  Bt = BtW1;  K = 256; Nn = 256; Npad = 256; }
  else if ((wb -= WB) < WB)          { W = Wr1; Bt = BtWr1; K = 256; Nn = 256; Npad = 256; }
  else if ((wb -= WB) < WB)          { W = W2;  Bt = BtW2;  K = 256; Nn = 256; Npad = 256; }
  else if ((wb -= WB) < WB)          { W = Wr2; Bt = BtWr2; K = 256; Nn = 256; Npad = 256; }
  else if ((wb -= WB) < LB)          { W = Wl1; Bt = BtWl1; K = 128; Nn = 256; Npad = 256; }
  else if ((wb -= LB) < LB)          { W = Wl2; Bt = BtWl2; K = 128; Nn = 256; Npad = 256; }
  else if ((wb -= LB) < FB)          { W = linW; Bt = BtLin; K = 256; Nn = DOUT; Npad = 384; }
  else {
    if (t < 256) {
      biasR1[t] = b1[t] + bl1[t];
      biasR2[t] = b2[t] + bl2[t];
    }
    for (int i = t; i < 384; i += 256) biasLin[i] = (i < DOUT) ? linb[i] : 0.f;
    return;
  }
  int idx = wb * 256 + t;
  int tot = Npad * K;
  if (idx >= tot) return;
  int nn = idx / K, k = idx - nn * K;
  float v = (nn < Nn) ? W[(size_t)k * Nn + nn] : 0.f;
  Bt[idx] = bf16_rn(v);
}

// -------- sort pass 2 (both edge types): bucket -> sorted + deg + off (+dinv) ---
#define MAXB 2560
__global__ __launch_bounds__(256) void sort_pass2(
    const u32* __restrict__ tmp, const int* __restrict__ prefix,
    const int* __restrict__ gcount, const int* __restrict__ lofs,
    int* __restrict__ cSorted, int* __restrict__ cDeg, int* __restrict__ cOff,
    int* __restrict__ wSorted, int* __restrict__ wDeg, int* __restrict__ wOff,
    float* __restrict__ dinv,
    int E, int nch, int n, int nbk) {
  const int bg = blockIdx.x, t = threadIdx.x;
  const int et = bg >= nbk;
  const int b = bg - et * nbk;
  int* outSorted = et ? wSorted : cSorted;
  int* deg = et ? wDeg : cDeg;
  int* offArr = et ? wOff : cOff;
  __shared__ u32 est[MAXB];
  __shared__ u32 outl[MAXB];
  __shared__ u32 cnt[128], ofs[128];
  __shared__ u32 sdata[256];

  const int node0 = b << 7;
  const size_t bgl = (size_t)et * NBKT + b;
  const int ebaseG = prefix[bgl * nch];
  const int eendG = (bg == 2 * nbk - 1) ? 2 * E : prefix[(bgl + 1) * nch];
  const int ebase = ebaseG - et * E;
  const int esize = (eendG - et * E) - ebase;

  const u32* tsrc = tmp + (size_t)et * nch * CHUNK;
  for (int c = t; c < nch; c += 256) {
    int g = lofs[((size_t)et * nch + c) * NBKT + b];
    int len = gcount[bgl * nch + c];
    int dp = prefix[bgl * nch + c] - ebaseG;
    for (int k = 0; k < len; ++k)
      est[dp + k] = tsrc[(size_t)c * CHUNK + g + k];
  }
  if (t < 128) cnt[t] = 0;
  __syncthreads();
  for (int i = t; i < esize; i += 256) atomicAdd(&cnt[est[i] & 127u], 1u);
  __syncthreads();
  u32 v = (t < 128) ? cnt[t] : 0;
  sdata[t] = v;
  __syncthreads();
  for (int o = 1; o < 256; o <<= 1) {
    u32 x = (t >= o) ? sdata[t - o] : 0;
    __syncthreads();
    sdata[t] += x;
    __syncthreads();
  }
  if (t < 128) ofs[t] = sdata[t] - v;
  __syncthreads();
  const int nNodes = (n - node0) < 128 ? (n - node0) : 128;
  if (t < nNodes) {
    deg[node0 + t] = (int)cnt[t];
    offArr[node0 + t] = ebase + (int)ofs[t];
    if (et == 0) dinv[node0 + t] = rsqrtf((float)(cnt[t] + 1));
  }
  __syncthreads();
  if (t < 128) cnt[t] = ofs[t];
  __syncthreads();
  for (int i = t; i < esize; i += 256) {
    u32 e = est[i];
    u32 p = atomicAdd(&cnt[e & 127u], 1u);
    outl[p] = e >> 7;
  }
  __syncthreads();
  for (int i = t; i < esize; i += 256) outSorted[ebase + i] = (int)outl[i];
}

// ---- wide gather bodies -------------------------------------------------------
// cites agg: row = 512B = 32 uint4; 32 lanes cover a row; 2 edges/wave (halves).
__device__ __forceinline__ void agg_body(
    const uint4* __restrict__ base, const float* __restrict__ dinv,
    const int* __restrict__ c_off, const int* __restrict__ c_cnt,
    const int* __restrict__ c_sorted, u16* __restrict__ xout,
    int d, int lane) {
  const int hl = lane & 31;
  const int half = lane >> 5;
  int start = c_off[d], cnt = c_cnt[d];
  float acc[8] = {};
  for (int j0 = 0; j0 < cnt; j0 += 64) {
    int nn = cnt - j0; nn = nn < 64 ? nn : 64;
    int sl = (j0 + lane < cnt) ? c_sorted[start + j0 + lane] : 0;
    int jj = 0;
    for (; jj + 8 <= nn; jj += 8) {  // 4 pairs = 8 edges
      int ss[4]; float dv[4]; uint4 vv[4];
#pragma unroll
      for (int u = 0; u < 4; ++u) ss[u] = __shfl(sl, jj + 2 * u + half);
#pragma unroll
      for (int u = 0; u < 4; ++u) dv[u] = dinv[ss[u]];
#pragma unroll
      for (int u = 0; u < 4; ++u) vv[u] = base[(size_t)ss[u] * 32 + hl];
#pragma unroll
      for (int u = 0; u < 4; ++u) {
        const u16* p = (const u16*)&vv[u];
#pragma unroll
        for (int e = 0; e < 8; ++e) acc[e] = fmaf(bf16f(p[e]), dv[u], acc[e]);
      }
    }
    for (; jj < nn; jj += 2) {  // pair tail, weight-masked
      int idx = jj + half;
      int s = __shfl(sl, idx < nn ? idx : jj);
      float wgt = (idx < nn) ? dinv[s] : 0.f;
      uint4 v = base[(size_t)s * 32 + hl];
      const u16* p = (const u16*)&v;
#pragma unroll
      for (int e = 0; e < 8; ++e) acc[e] = fmaf(bf16f(p[e]), wgt, acc[e]);
    }
  }
  float dd = dinv[d];
  {
    uint4 v = base[(size_t)d * 32 + hl];
    float wgt = half ? 0.f : dd;   // self row added once
    const u16* p = (const u16*)&v;
#pragma unroll
    for (int e = 0; e < 8; ++e) acc[e] = fmaf(bf16f(p[e]), wgt, acc[e]);
  }
  float f[8];
#pragma unroll
  for (int e = 0; e < 8; ++e) f[e] = (acc[e] + __shfl_xor(acc[e], 32)) * dd;
  if (lane < 32) {
    uint4 O;
    O.x = pack2(f[0], f[1]); O.y = pack2(f[2], f[3]);
    O.z = pack2(f[4], f[5]); O.w = pack2(f[6], f[7]);
    ((uint4*)xout)[(size_t)d * 32 + hl] = O;
  }
}

// author mean: row = 256B = 16 uint4; 16 lanes cover a row; 4 edges/wave.
__device__ __forceinline__ void mean_body(
    const uint4* __restrict__ xa, const int* __restrict__ w_off,
    const int* __restrict__ w_cnt, const int* __restrict__ w_sorted,
    u16* __restrict__ mean, int d, int lane) {
  const int hl = lane & 15;
  const int qt = lane >> 4;
  int start = w_off[d], cnt = w_cnt[d];
  float acc[8] = {};
  for (int j0 = 0; j0 < cnt; j0 += 64) {
    int nn = cnt - j0; nn = nn < 64 ? nn : 64;
    int sl = (j0 + lane < cnt) ? w_sorted[start + j0 + lane] : 0;
    int jj = 0;
    for (; jj + 8 <= nn; jj += 8) {  // 2 quads = 8 edges
      int ss[2]; uint4 vv[2];
#pragma unroll
      for (int u = 0; u < 2; ++u) ss[u] = __shfl(sl, jj + 4 * u + qt);
#pragma unroll
      for (int u = 0; u < 2; ++u) vv[u] = xa[(size_t)ss[u] * 16 + hl];
#pragma unroll
      for (int u = 0; u < 2; ++u) {
        const u16* p = (const u16*)&vv[u];
#pragma unroll
        for (int e = 0; e < 8; ++e) acc[e] += bf16f(p[e]);
      }
    }
    for (; jj < nn; jj += 4) {  // quad tail, weight-masked
      int idx = jj + qt;
      int s = __shfl(sl, idx < nn ? idx : jj);
      float wgt = (idx < nn) ? 1.f : 0.f;
      uint4 v = xa[(size_t)s * 16 + hl];
      const u16* p = (const u16*)&v;
#pragma unroll
      for (int e = 0; e < 8; ++e) acc[e] = fmaf(bf16f(p[e]), wgt, acc[e]);
    }
  }
  float inv = 1.0f / (float)((cnt > 0) ? cnt : 1);
  float f[8];
#pragma unroll
  for (int e = 0; e < 8; ++e) {
    float x = acc[e] + __shfl_xor(acc[e], 16);
    x += __shfl_xor(x, 32);
    f[e] = x * inv;
  }
  if (lane < 16) {
    uint4 O;
    O.x = pack2(f[0], f[1]); O.y = pack2(f[2], f[3]);
    O.z = pack2(f[4], f[5]); O.w = pack2(f[6], f[7]);
    ((uint4*)mean)[(size_t)d * 16 + hl] = O;
  }
}

// -------- fused gather: blocks [0,nbw) = cites agg; [nbw,2*nbw) = author mean --
__global__ void gather_fused(
    const u16* __restrict__ xin, const float* __restrict__ dinv,
    const int* __restrict__ c_off, const int* __restrict__ c_cnt,
    const int* __restrict__ c_sorted, u16* __restrict__ xout,
    const u16* __restrict__ xa16, const int* __restrict__ w_off,
    const int* __restrict__ w_cnt, const int* __restrict__ w_sorted,
    u16* __restrict__ mean, int n, int nbw) {
  const int lane = threadIdx.x & 63;
  if (blockIdx.x < nbw) {
    int d = ((blockIdx.x * blockDim.x) >> 6) + (threadIdx.x >> 6);
    if (d >= n) return;
    agg_body((const uint4*)xin, dinv, c_off, c_cnt, c_sorted, xout, d, lane);
  } else {
    int d = (((blockIdx.x - nbw) * blockDim.x) >> 6) + (threadIdx.x >> 6);
    if (d >= n) return;
    mean_body((const uint4*)xa16, w_off, w_cnt, w_sorted, mean, d, lane);
  }
}

// ---------------- agg_gcn standalone (layer 2) ----------------
__global__ void agg_gcn(const u16* __restrict__ xin, const float* __restrict__ dinv,
                        const int* __restrict__ c_off, const int* __restrict__ c_cnt,
                        const int* __restrict__ c_sorted,
                        u16* __restrict__ xout, int n) {
  int d = (blockIdx.x * blockDim.x + threadIdx.x) >> 6;
  int lane = threadIdx.x & 63;
  if (d >= n) return;
  agg_body((const uint4*)xin, dinv, c_off, c_cnt, c_sorted, xout, d, lane);
}

// ------------- bf16 MFMA GEMM: tile 128x128, 4 waves (2x2), 32KB LDS ----------
template <int NSEG, bool F32OUT, int NC>
__global__ __launch_bounds__(256, 4) void gemm_bf16(
    const u16* __restrict__ A0, const u16* __restrict__ A1, const u16* __restrict__ A2,
    const u16* __restrict__ B0, const u16* __restrict__ B1, const u16* __restrict__ B2,
    const float* __restrict__ bias,
    u16* __restrict__ Cp, float* __restrict__ Cf,
    int M, int N) {
  __shared__ u16 Ah[2][4096];
  __shared__ u16 Bh[2][4096];

  const int t = threadIdx.x;
  const int wid = t >> 6, lane = t & 63;
  const int wr = wid >> 1, wc = wid & 1;
  const int lrow = lane & 15, kslot = lane >> 4;
  const int jsw = kslot ^ ((lrow >> 1) & 3);

  const int nb = gridDim.x;
  const int q = nb >> 3, r = nb & 7;
  const int xcd = blockIdx.x & 7, pos = blockIdx.x >> 3;
  const int lin = (xcd < r ? xcd * (q + 1) : r * (q + 1) + (xcd - r) * q) + pos;
  const int bx = lin / NC, by = lin - bx * NC;
  const int gm = bx * 128;
  const int gn = by * 128;

  const int s_r = lane >> 2;
  const int s_j = (lane & 3) ^ ((s_r >> 1) & 3);

  f32x4 acc[4][4];
  const f32x4 z4 = {0.f, 0.f, 0.f, 0.f};
#pragma unroll
  for (int m = 0; m < 4; ++m)
#pragma unroll
    for (int n = 0; n < 4; ++n) acc[m][n] = z4;

  const int NT = (NSEG == 3) ? 20 : 8;

  auto STAGE = [&](int tt, int half) {
    const u16* A;
    const u16* B;
    int rs, k0;
    if (NSEG == 3 && tt >= 16)     { A = A2; B = B2; rs = 128; k0 = (tt - 16) * 32; }
    else if (NSEG == 3 && tt >= 8) { A = A1; B = B1; rs = 256; k0 = (tt - 8) * 32; }
    else                           { A = A0; B = B0; rs = 256; k0 = tt * 32; }
    const int c = wid * 2;
#pragma unroll
    for (int cc = 0; cc < 2; ++cc) {
      int grow = gm + (c + cc) * 16 + s_r;
      grow = grow < M ? grow : M - 1;
      gload16(A + (size_t)grow * rs + (k0 + s_j * 8), &Ah[half][(c + cc) * 512]);
      int col = gn + (c + cc) * 16 + s_r;
      gload16(B + (size_t)col * rs + (k0 + s_j * 8), &Bh[half][(c + cc) * 512]);
    }
  };

  STAGE(0, 0);
  __syncthreads();

  for (int tt = 0; tt < NT; ++tt) {
    const int half = tt & 1;
    if (tt + 1 < NT) STAGE(tt + 1, half ^ 1);

    bf16x8 ah[4];
    const int ab = (wr * 64 + lrow) * 32 + jsw * 8;
#pragma unroll
    for (int m = 0; m < 4; ++m) ah[m] = *(const bf16x8*)&Ah[half][ab + m * 512];
    const int bb = (wc * 64 + lrow) * 32 + jsw * 8;
#pragma unroll
    for (int n = 0; n < 4; ++n) {
      bf16x8 bn = *(const bf16x8*)&Bh[half][bb + n * 512];
#pragma unroll
      for (int m = 0; m < 4; ++m)
        acc[m][n] = __builtin_amdgcn_mfma_f32_16x16x32_bf16(ah[m], bn, acc[m][n], 0, 0, 0);
    }
    __syncthreads();
  }

  const int col0 = gn + wc * 64 + lrow;
  const int row00 = gm + wr * 64 + kslot * 4;
#pragma unroll
  for (int m = 0; m < 4; ++m) {
#pragma unroll
    for (int i = 0; i < 4; ++i) {
      int row = row00 + m * 16 + i;
      if (row >= M) continue;
#pragma unroll
      for (int n = 0; n < 4; ++n) {
        int col = col0 + n * 16;
        float v = acc[m][n][i] + bias[col];
        if (F32OUT) {
          if (col < N) Cf[(size_t)row * N + col] = v;
        } else {
          Cp[(size_t)row * 256 + col] = bf16_rn(fmaxf(v, 0.f));
        }
      }
    }
  }
}

// ---------------- launch ----------------
static inline size_t align_up(size_t x) { return (x + 255) & ~(size_t)255; }

extern "C" void kernel_launch(void* const* d_in, const int* in_sizes, int n_in,
                              void* d_out, int out_size, void* d_ws, size_t ws_size,
                              hipStream_t stream) {
  const float* x_paper  = (const float*)d_in[0];
  const float* x_author = (const float*)d_in[1];
  const int*   cites    = (const int*)d_in[2];
  const int*   w_src    = (const int*)d_in[3];
  const int*   w_dst    = (const int*)d_in[4];
  const float* W1  = (const float*)d_in[5];
  const float* b1  = (const float*)d_in[6];
  const float* Wl1 = (const float*)d_in[7];
  const float* bl1 = (const float*)d_in[8];
  const float* Wr1 = (const float*)d_in[9];
  const float* W2  = (const float*)d_in[10];
  const float* b2  = (const float*)d_in[11];
  const float* Wl2 = (const float*)d_in[12];
  const float* bl2 = (const float*)d_in[13];
  const float* Wr2 = (const float*)d_in[14];
  const float* linW = (const float*)d_in[15];
  const float* linb = (const float*)d_in[16];
  float* out = (float*)d_out;

  const int N = in_sizes[0] / DP;       // 100000
  const int NA = in_sizes[1] / DA;      // 50000
  const int E = in_sizes[3];            // 1000000
  const int* c_src = cites;
  const int* c_dst = cites + E;

  const int NCH = (E + CHUNK - 1) / CHUNK;       // 245
  const int NB = (N + 127) >> 7;                 // 782
  const int GC2 = 2 * NB * NCH;

  char* w = (char*)d_ws;
  size_t off = 0;
  auto alloc = [&](size_t bytes) -> void* {
    void* p = w + off;
    off = align_up(off + bytes);
    return p;
  };
  int* deg_c      = (int*)alloc((size_t)N * 4);
  int* cnt_w      = (int*)alloc((size_t)N * 4);
  int* cites_off  = (int*)alloc((size_t)N * 4);
  int* writes_off = (int*)alloc((size_t)N * 4);
  int* c_sorted   = (int*)alloc((size_t)E * 4);
  int* w_sorted   = (int*)alloc((size_t)E * 4);
  u32* tmpE       = (u32*)alloc((size_t)2 * NCH * CHUNK * 4);
  int* gcount     = (int*)alloc((size_t)GC2 * 4);
  int* gprefix    = (int*)alloc((size_t)GC2 * 4);
  int* lofs       = (int*)alloc((size_t)2 * NCH * NBKT * 4);
  int* bsumA      = (int*)alloc(256 * 4);
  float* dinv     = (float*)alloc((size_t)N * 4);
  u16* xa16       = (u16*)alloc((size_t)NA * DA * 2);
  u16* meanA      = (u16*)alloc((size_t)N * DA * 2);
  u16* xp         = (u16*)alloc((size_t)N * 256 * 2);
  u16* xs         = (u16*)alloc((size_t)N * 256 * 2);
  u16* pb         = (u16*)alloc((size_t)N * 256 * 2);
  const int bsW = 256 * 256, bsL = 256 * 128, bsLin = 384 * 256;
  u16* BtW1  = (u16*)alloc((size_t)bsW * 2);
  u16* BtWr1 = (u16*)alloc((size_t)bsW * 2);
  u16* BtW2  = (u16*)alloc((size_t)bsW * 2);
  u16* BtWr2 = (u16*)alloc((size_t)bsW * 2);
  u16* BtWl1 = (u16*)alloc((size_t)bsL * 2);
  u16* BtWl2 = (u16*)alloc((size_t)bsL * 2);
  u16* BtLin = (u16*)alloc((size_t)bsLin * 2);
  float* biasR1  = (float*)alloc(256 * 4);
  float* biasR2  = (float*)alloc(256 * 4);
  float* biasLin = (float*)alloc(384 * 4);
  (void)ws_size; (void)n_in; (void)out_size;

  const int nsb2 = (GC2 + SCAN_TILE - 1) / SCAN_TILE;

  // ---- fused CSR pass1 + prep (independent tracks, co-scheduled) ----
  {
    const int R1 = (N * 32 + 255) / 256;
    const int R2 = R1 + (NA * 16 + 255) / 256;
    const int PREP = R2 + 4 * 256 + 2 * 128 + 384 + 1;
    sort1_prep<<<2 * NCH + PREP, 256, 0, stream>>>(
        c_src, c_dst, w_src, w_dst, tmpE, gcount, lofs, E, NCH,
        x_paper, x_author, xp, xa16,
        W1, Wr1, W2, Wr2, Wl1, Wl2, linW,
        BtW1, BtWr1, BtW2, BtWr2, BtWl1, BtWl2, BtLin,
        b1, bl1, b2, bl2, linb, biasR1, biasR2, biasLin, N, NA);
  }
  scan_local<<<nsb2, SCAN_TPB, 0, stream>>>(gcount, gprefix, bsumA, GC2);
  scan_spine<<<1, 256, 0, stream>>>(bsumA, nsb2);
  scan_add<<<nsb2, SCAN_TPB, 0, stream>>>(gprefix, bsumA, GC2);
  sort_pass2<<<2 * NB, 256, 0, stream>>>(tmpE, gprefix, gcount, lofs,
                                         c_sorted, deg_c, cites_off,
                                         w_sorted, cnt_w, writes_off,
                                         dinv, E, NCH, N, NB);

  const int nbWave = (N * 64 + 255) / 256;
  const int GX = (N + 127) / 128;  // 782

  // layer 1: fused agg(cites) + author-mean
  gather_fused<<<2 * nbWave, 256, 0, stream>>>(
      xp, dinv, cites_off, deg_c, c_sorted, xs,
      xa16, writes_off, cnt_w, w_sorted, meanA, N, nbWave);
  gemm_bf16<3, false, 2><<<GX * 2, 256, 0, stream>>>(
      xs, xp, meanA, BtW1, BtWr1, BtWl1, biasR1, pb, nullptr, N, HIDN);
  // layer 2
  agg_gcn<<<nbWave, 256, 0, stream>>>(pb, dinv, cites_off, deg_c, c_sorted, xs, N);
  gemm_bf16<3, false, 2><<<GX * 2, 256, 0, stream>>>(
      xs, pb, meanA, BtW2, BtWr2, BtWl2, biasR2, xp, nullptr, N, HIDN);
  // output projection: 3 col tiles of 128 (384 >= 349)
  gemm_bf16<1, true, 3><<<GX * 3, 256, 0, stream>>>(
      xp, nullptr, nullptr, BtLin, nullptr, nullptr, biasLin, nullptr, out, N, DOUT);
}